// Round 1
// baseline (373.584 us; speedup 1.0000x reference)
//
#include <hip/hip_runtime.h>
#include <hip/hip_bf16.h>

// HyperPatchConv2d: B=2, CIN=COUT=64, H=W=256, FH=FW=16 (patch 16x16), SC=128, K=3, reflect pad 1.
// Kernel 1: weight-gen GEMM  Wdyn[patch][p] = sum_c s2w[p][c] * s[b][c][f][g]   (bf16 out -> d_ws)
// Kernel 2: per-patch conv   out[b,co,f*16+p,g*16+q] = sum_{ci,i,j} W * x_reflect[...]

#define C_OUT 64
#define C_IN  64
#define P_TOTAL (C_OUT * C_IN * 9)   // 36864
#define N_PATCH 512                  // B * 16 * 16

__device__ __forceinline__ unsigned short f2bf(float f) {
  unsigned int u = __float_as_uint(f);
  u += 0x7fffu + ((u >> 16) & 1u);   // round-to-nearest-even on bf16 boundary
  return (unsigned short)(u >> 16);
}
__device__ __forceinline__ float bfLO(unsigned int u) { return __uint_as_float(u << 16); }
__device__ __forceinline__ float bfHI(unsigned int u) { return __uint_as_float(u & 0xffff0000u); }

// ---------------- Kernel 1: weight generation GEMM ----------------
// Block tile: 64 p-rows x 64 patch-cols, K=128 in chunks of 32. 256 threads, 4x4 micro-tile.
__global__ __launch_bounds__(256) void wgen_kernel(
    const float* __restrict__ s2w,   // [36864][128]
    const float* __restrict__ s,     // [2][128][16][16]
    unsigned short* __restrict__ wout) // bf16 bits [512][36864]
{
  __shared__ float As[32][68];   // [k][m] +4 pad
  __shared__ float Bs[32][68];   // [k][n]
  const int tid = threadIdx.x;
  const int tx = tid & 15, ty = tid >> 4;
  const int p0 = blockIdx.x * 64;
  const int n0 = blockIdx.y * 64;          // patch-col tile base (never crosses b: 64 | 256)
  const int bb = n0 >> 8;
  const int fg0 = n0 & 255;
  float acc[4][4] = {};

  for (int kk0 = 0; kk0 < 128; kk0 += 32) {
    { // A: 64 rows x 32 k; thread: row m = tid>>2, 8 consecutive k
      const int m = tid >> 2;
      const int k4 = (tid & 3) * 8;
      const float4* src = (const float4*)(s2w + (size_t)(p0 + m) * 128 + kk0 + k4);
      const float4 v0 = src[0], v1 = src[1];
      As[k4+0][m]=v0.x; As[k4+1][m]=v0.y; As[k4+2][m]=v0.z; As[k4+3][m]=v0.w;
      As[k4+4][m]=v1.x; As[k4+5][m]=v1.y; As[k4+6][m]=v1.z; As[k4+7][m]=v1.w;
    }
    { // B: 32 k x 64 cols; thread: k = tid>>3, 8 consecutive cols
      const int k = tid >> 3;
      const int n8 = (tid & 7) * 8;
      const float* src = s + (size_t)(bb * 128 + kk0 + k) * 256 + fg0 + n8;
      const float4 v0 = *(const float4*)src;
      const float4 v1 = *(const float4*)(src + 4);
      Bs[k][n8+0]=v0.x; Bs[k][n8+1]=v0.y; Bs[k][n8+2]=v0.z; Bs[k][n8+3]=v0.w;
      Bs[k][n8+4]=v1.x; Bs[k][n8+5]=v1.y; Bs[k][n8+6]=v1.z; Bs[k][n8+7]=v1.w;
    }
    __syncthreads();
    #pragma unroll
    for (int k = 0; k < 32; ++k) {
      const float4 a = *(const float4*)&As[k][ty * 4];
      const float4 b = *(const float4*)&Bs[k][tx * 4];
      acc[0][0] += a.x*b.x; acc[0][1] += a.x*b.y; acc[0][2] += a.x*b.z; acc[0][3] += a.x*b.w;
      acc[1][0] += a.y*b.x; acc[1][1] += a.y*b.y; acc[1][2] += a.y*b.z; acc[1][3] += a.y*b.w;
      acc[2][0] += a.z*b.x; acc[2][1] += a.z*b.y; acc[2][2] += a.z*b.z; acc[2][3] += a.z*b.w;
      acc[3][0] += a.w*b.x; acc[3][1] += a.w*b.y; acc[3][2] += a.w*b.z; acc[3][3] += a.w*b.w;
    }
    __syncthreads();
  }
  #pragma unroll
  for (int j = 0; j < 4; ++j) {
    const int col = n0 + tx * 4 + j;
    unsigned short* dst = wout + (size_t)col * P_TOTAL + p0 + ty * 4;
    ushort4 pk;
    pk.x = f2bf(acc[0][j]); pk.y = f2bf(acc[1][j]);
    pk.z = f2bf(acc[2][j]); pk.w = f2bf(acc[3][j]);
    *(ushort4*)dst = pk;
  }
}

// ---------------- Kernel 2: per-patch dynamic conv ----------------
// Block = (patch, cout-quarter). LDS: window bf16 [64][18][18] (41.5KB) + weights bf16
// [16][64][10] (20.5KB, stride-10 pad keeps uint loads 4B-aligned). Thread: 1 cout x 4x4 pixels.
__global__ __launch_bounds__(256) void conv_kernel(
    const float* __restrict__ x,            // [2][64][256][256]
    const unsigned short* __restrict__ wsrc, // bf16 [512][36864]
    float* __restrict__ out)                // [2][64][256][256]
{
  __shared__ unsigned short win[C_IN * 18 * 18];
  __shared__ unsigned short wts[16 * 64 * 10];
  const int tid = threadIdx.x;
  const int patch = blockIdx.x;
  const int cq = blockIdx.y;          // 0..3 -> couts cq*16..+15
  const int bb = patch >> 8;
  const int fg = patch & 255;
  const int f = fg >> 4, g = fg & 15;
  const int row0 = f * 16, col0 = g * 16;

  // Stage window (reflect-padded 18x18 halo per ci)
  for (int idx = tid; idx < C_IN * 324; idx += 256) {
    const int ci = idx / 324;
    const int rem = idx - ci * 324;
    const int r = rem / 18;
    const int c = rem - r * 18;
    int rr = row0 + r - 1; rr = rr < 0 ? -rr : (rr > 255 ? 510 - rr : rr);
    int cc = col0 + c - 1; cc = cc < 0 ? -cc : (cc > 255 ? 510 - cc : cc);
    win[idx] = f2bf(x[(((size_t)bb * C_IN + ci) << 16) + (rr << 8) + cc]);
  }
  // Stage this quarter's weights (contiguous 9216 bf16), re-strided 9 -> 10
  const unsigned short* wp = wsrc + (size_t)patch * P_TOTAL + cq * 9216;
  for (int l = tid; l < 9216; l += 256) {
    const int co = l / 576;
    const int rem = l - co * 576;     // ci*9 + t
    const int ci = rem / 9;
    const int t = rem - ci * 9;
    wts[(co * 64 + ci) * 10 + t] = wp[l];
  }
  __syncthreads();

  const int co_l = tid >> 4;
  const int slot = tid & 15;
  const int pb = (slot >> 2) * 4;
  const int qb = (slot & 3) * 4;
  float acc[4][4] = {};
  const unsigned short* wrow = wts + co_l * 640;

  for (int ci = 0; ci < C_IN; ++ci) {
    const unsigned int* wpp = (const unsigned int*)(wrow + ci * 10);
    const unsigned int u0 = wpp[0], u1 = wpp[1], u2 = wpp[2], u3 = wpp[3], u4 = wpp[4];
    float wt[9];
    wt[0] = bfLO(u0); wt[1] = bfHI(u0); wt[2] = bfLO(u1); wt[3] = bfHI(u1);
    wt[4] = bfLO(u2); wt[5] = bfHI(u2); wt[6] = bfLO(u3); wt[7] = bfHI(u3);
    wt[8] = bfLO(u4);

    float wv[6][6];
    const int base = ci * 324 + pb * 18 + qb;   // even -> 4B aligned
    #pragma unroll
    for (int rr = 0; rr < 6; ++rr) {
      const unsigned int* q = (const unsigned int*)(win + base + rr * 18);
      const unsigned int a0 = q[0], a1 = q[1], a2 = q[2];
      wv[rr][0] = bfLO(a0); wv[rr][1] = bfHI(a0); wv[rr][2] = bfLO(a1);
      wv[rr][3] = bfHI(a1); wv[rr][4] = bfLO(a2); wv[rr][5] = bfHI(a2);
    }
    #pragma unroll
    for (int i = 0; i < 3; ++i)
      #pragma unroll
      for (int j = 0; j < 3; ++j) {
        const float w = wt[i * 3 + j];
        #pragma unroll
        for (int pp = 0; pp < 4; ++pp)
          #pragma unroll
          for (int qq = 0; qq < 4; ++qq)
            acc[pp][qq] += w * wv[pp + i][qq + j];
      }
  }

  const int co = cq * 16 + co_l;
  #pragma unroll
  for (int pp = 0; pp < 4; ++pp) {
    const float4 v = make_float4(acc[pp][0], acc[pp][1], acc[pp][2], acc[pp][3]);
    *(float4*)(out + (((size_t)bb * C_OUT + co) << 16) + ((size_t)(row0 + pb + pp) << 8) + col0 + qb) = v;
  }
}

extern "C" void kernel_launch(void* const* d_in, const int* in_sizes, int n_in,
                              void* d_out, int out_size, void* d_ws, size_t ws_size,
                              hipStream_t stream) {
  const float* x   = (const float*)d_in[0];   // [2,64,256,256]
  const float* s   = (const float*)d_in[1];   // [2,128,16,16]
  const float* s2w = (const float*)d_in[2];   // [36864,128]
  float* out = (float*)d_out;
  unsigned short* wbuf = (unsigned short*)d_ws;  // bf16 [512][36864] = 37.7 MB

  wgen_kernel<<<dim3(P_TOTAL / 64, N_PATCH / 64), 256, 0, stream>>>(s2w, s, wbuf);
  conv_kernel<<<dim3(N_PATCH, 4), 256, 0, stream>>>(x, wbuf, out);
}

// Round 2
// 188.193 us; speedup vs baseline: 1.9851x; 1.9851x over previous
//
#include <hip/hip_runtime.h>
#include <hip/hip_bf16.h>

// HyperPatchConv2d: B=2, CIN=COUT=64, H=W=256, FH=FW=16 (16x16 patches), SC=128, K=3, reflect pad.
// Kernel 1 (wgen): fp32 GEMM  W[patch, p] = sum_c s2w[p,c] * s[b,c,f,g], p=(co,ci,tap) co-major.
//   Writes bf16 weights to d_ws in MFMA A-fragment order: [patch][tap][ks][mt][lane][8 ci].
// Kernel 2 (conv): per-patch MFMA GEMM, 9 tap-GEMMs of K=64:
//   out[co, px] += sum_ci W_tap[co,ci] * win[ci, px_shifted(tap)]  via mfma_f32_16x16x32_bf16.

#define C_OUT 64
#define C_IN  64
#define P_TOTAL (C_OUT * C_IN * 9)   // 36864
#define N_PATCH 512                  // B * 16 * 16
#define WSTR 72                      // shorts per (r,c) cell in window LDS (16B-aligned rows, 2-way banks)

typedef __bf16 bf16x8 __attribute__((ext_vector_type(8)));
typedef float  f32x4  __attribute__((ext_vector_type(4)));

__device__ __forceinline__ unsigned short f2bf(float f) {
  unsigned int u = __float_as_uint(f);
  u += 0x7fffu + ((u >> 16) & 1u);   // RTNE on bf16 boundary
  return (unsigned short)(u >> 16);
}

// ---------------- Kernel 1: weight generation GEMM ----------------
// Grid: (576, 8). blockIdx.x -> (co, tap); block M-dim = 64 ci rows (p = co*576 + 9*ci + tap),
// N-dim = 64 patches. K = 128 in chunks of 32. 256 threads, 4x4 micro-tile.
// Thread (ty,tx) owns ci = ty*4..+3 (consecutive -> ushort4 fragment write), patches tx*4..+3.
__global__ __launch_bounds__(256) void wgen_kernel(
    const float* __restrict__ s2w,     // [36864][128]
    const float* __restrict__ s,       // [2][128][16][16]
    unsigned short* __restrict__ wout) // bf16 frags [512][36864]
{
  __shared__ float As[32][68];   // [k][m=ci] +4 pad
  __shared__ float Bs[32][68];   // [k][n=patch]
  const int tid = threadIdx.x;
  const int tx = tid & 15, ty = tid >> 4;
  const int co  = blockIdx.x / 9;
  const int tap = blockIdx.x - co * 9;
  const int n0 = blockIdx.y * 64;          // patch base (64 | 256 -> never crosses b)
  const int bb = n0 >> 8;
  const int fg0 = n0 & 255;
  float acc[4][4] = {};
  const float* arow = s2w + ((size_t)co * 576 + tap) * 128;

  for (int kk0 = 0; kk0 < 128; kk0 += 32) {
    { // A: 64 ci-rows x 32 k; thread: ci = tid>>2, 8 consecutive k
      const int m = tid >> 2;
      const int k8 = (tid & 3) * 8;
      const float* src = arow + (size_t)(9 * m) * 128 + kk0 + k8;
      const float4 v0 = *(const float4*)src;
      const float4 v1 = *(const float4*)(src + 4);
      As[k8+0][m]=v0.x; As[k8+1][m]=v0.y; As[k8+2][m]=v0.z; As[k8+3][m]=v0.w;
      As[k8+4][m]=v1.x; As[k8+5][m]=v1.y; As[k8+6][m]=v1.z; As[k8+7][m]=v1.w;
    }
    { // B: 32 k x 64 patch-cols; thread: k = tid>>3, 8 consecutive cols
      const int k = tid >> 3;
      const int n8 = (tid & 7) * 8;
      const float* src = s + (size_t)(bb * 128 + kk0 + k) * 256 + fg0 + n8;
      const float4 v0 = *(const float4*)src;
      const float4 v1 = *(const float4*)(src + 4);
      Bs[k][n8+0]=v0.x; Bs[k][n8+1]=v0.y; Bs[k][n8+2]=v0.z; Bs[k][n8+3]=v0.w;
      Bs[k][n8+4]=v1.x; Bs[k][n8+5]=v1.y; Bs[k][n8+6]=v1.z; Bs[k][n8+7]=v1.w;
    }
    __syncthreads();
    #pragma unroll
    for (int k = 0; k < 32; ++k) {
      const float4 a = *(const float4*)&As[k][ty * 4];
      const float4 b = *(const float4*)&Bs[k][tx * 4];
      acc[0][0] += a.x*b.x; acc[0][1] += a.x*b.y; acc[0][2] += a.x*b.z; acc[0][3] += a.x*b.w;
      acc[1][0] += a.y*b.x; acc[1][1] += a.y*b.y; acc[1][2] += a.y*b.z; acc[1][3] += a.y*b.w;
      acc[2][0] += a.z*b.x; acc[2][1] += a.z*b.y; acc[2][2] += a.z*b.z; acc[2][3] += a.z*b.w;
      acc[3][0] += a.w*b.x; acc[3][1] += a.w*b.y; acc[3][2] += a.w*b.z; acc[3][3] += a.w*b.w;
    }
    __syncthreads();
  }

  // Fragment-order write. ci = ty*4 + r. frag addr:
  //   ((tap*2 + ks)*4 + mt)*512 + lane*8 + (ci&7), lane = (co&15) + 16*((ci>>3)&3)
  const int ks   = ty >> 3;
  const int quad = (ty >> 1) & 3;
  const int j0   = (ty & 1) * 4;
  const size_t fragoff =
      (size_t)(((tap * 2 + ks) * 4 + (co >> 4)) * 64 + (co & 15) + 16 * quad) * 8 + j0;
  #pragma unroll
  for (int j = 0; j < 4; ++j) {
    const int patch = n0 + tx * 4 + j;
    ushort4 pk;
    pk.x = f2bf(acc[0][j]); pk.y = f2bf(acc[1][j]);
    pk.z = f2bf(acc[2][j]); pk.w = f2bf(acc[3][j]);
    *(ushort4*)(wout + (size_t)patch * P_TOTAL + fragoff) = pk;
  }
}

// ---------------- Kernel 2: per-patch MFMA conv ----------------
// One block (256 thr = 4 waves) per patch. Window bf16 channel-last in LDS:
// win[r][c][ci], r,c in 0..17, ci-stride WSTR=72 shorts (46.7 KB -> 3 blocks/CU).
// Wave w computes output rows p = w*4..w*4+3 (4 N-tiles of 16 px) x all 64 co (4 M-tiles).
// 9 tap-GEMMs of K=64 (2 MFMA K-steps): 288 mfma_f32_16x16x32_bf16 per wave.
__global__ __launch_bounds__(256) void conv_kernel(
    const float* __restrict__ x,              // [2][64][256][256]
    const unsigned short* __restrict__ wfrag, // bf16 frags [512][36864]
    float* __restrict__ out)                  // [2][64][256][256]
{
  __shared__ unsigned short win[18 * 18 * WSTR];   // 46656 B
  const int tid = threadIdx.x;
  const int patch = blockIdx.x;
  const int bb = patch >> 8;
  const int fg = patch & 255;
  const int f = fg >> 4, g = fg & 15;
  const int row0 = f * 16, col0 = g * 16;

  // Stage window: read x coalesced (c fastest), write channel-last.
  for (int idx = tid; idx < C_IN * 324; idx += 256) {   // 81 iters exactly
    const int ci = idx / 324;
    const int rem = idx - ci * 324;
    const int r = rem / 18;
    const int c = rem - r * 18;
    int rr = row0 + r - 1; rr = rr < 0 ? -rr : (rr > 255 ? 510 - rr : rr);
    int cc = col0 + c - 1; cc = cc < 0 ? -cc : (cc > 255 ? 510 - cc : cc);
    win[(r * 18 + c) * WSTR + ci] = f2bf(x[(((size_t)bb * C_IN + ci) << 16) + (rr << 8) + cc]);
  }
  __syncthreads();

  const int wave = tid >> 6;
  const int lane = tid & 63;
  const int t = lane & 15;        // B free dim: pixel column q
  const int quad = lane >> 4;

  f32x4 acc[4][4] = {};           // [mt=co/16][nt=p row]
  const bf16x8* wb = (const bf16x8*)(wfrag + (size_t)patch * P_TOTAL);

  for (int tap = 0; tap < 9; ++tap) {
    const int ti = tap / 3;       // i (row offset)
    const int tj = tap - ti * 3;  // j (col offset)
    bf16x8 afr[2][4];
    #pragma unroll
    for (int ks = 0; ks < 2; ++ks)
      #pragma unroll
      for (int mt = 0; mt < 4; ++mt)
        afr[ks][mt] = wb[((tap * 2 + ks) * 4 + mt) * 64 + lane];

    #pragma unroll
    for (int nt = 0; nt < 4; ++nt) {
      const int r = wave * 4 + nt + ti;            // window row index
      const int c = t + tj;                        // window col index
      const int base = (r * 18 + c) * WSTR + quad * 8;
      #pragma unroll
      for (int ks = 0; ks < 2; ++ks) {
        const bf16x8 bfr = *(const bf16x8*)&win[base + ks * 32];
        #pragma unroll
        for (int mt = 0; mt < 4; ++mt)
          acc[mt][nt] = __builtin_amdgcn_mfma_f32_16x16x32_bf16(afr[ks][mt], bfr, acc[mt][nt], 0, 0, 0);
      }
    }
  }

  // Epilogue: D layout col=lane&15 (pixel q), row=(lane>>4)*4+reg (co within M-tile).
  #pragma unroll
  for (int mt = 0; mt < 4; ++mt) {
    #pragma unroll
    for (int nt = 0; nt < 4; ++nt) {
      const int p = row0 + wave * 4 + nt;
      #pragma unroll
      for (int reg = 0; reg < 4; ++reg) {
        const int co = mt * 16 + quad * 4 + reg;
        out[(((size_t)bb * C_OUT + co) << 16) + ((size_t)p << 8) + col0 + t] = acc[mt][nt][reg];
      }
    }
  }
}

extern "C" void kernel_launch(void* const* d_in, const int* in_sizes, int n_in,
                              void* d_out, int out_size, void* d_ws, size_t ws_size,
                              hipStream_t stream) {
  const float* x   = (const float*)d_in[0];   // [2,64,256,256]
  const float* s   = (const float*)d_in[1];   // [2,128,16,16]
  const float* s2w = (const float*)d_in[2];   // [36864,128]
  float* out = (float*)d_out;
  unsigned short* wbuf = (unsigned short*)d_ws;  // bf16 frags [512][36864] = 37.7 MB

  wgen_kernel<<<dim3(C_OUT * 9, N_PATCH / 64), 256, 0, stream>>>(s2w, s, wbuf);
  conv_kernel<<<N_PATCH, 256, 0, stream>>>(x, wbuf, out);
}

// Round 3
// 156.172 us; speedup vs baseline: 2.3921x; 1.2050x over previous
//
#include <hip/hip_runtime.h>
#include <hip/hip_bf16.h>

// HyperPatchConv2d: B=2, CIN=COUT=64, H=W=256, FH=FW=16 (16x16 patches), SC=128, K=3, reflect pad.
// Pipeline:
//   prep_s2w: s2w fp32 [36864][128] -> A0 bf16 [36864][128], M-dim permuted to m=(co,tap,ci)
//   prep_s:   s fp32 [2][128][256]  -> sT bf16 [512 patch][128 k]
//   prep_x:   x fp32 [2][64][256][256] -> xT bf16 [2][256][256][64ci]  (channel-last)
//   wgen:     MFMA GEMM C[m,patch] = sum_k A0[m,k]*sT[patch,k]; epilogue scatters ushort4
//             into conv A-fragment order: [patch][tap][ks][mt][lane][8ci]
//   conv:     per-patch 9-tap MFMA GEMM (verified round-2 core), window staged from xT.

#define C_OUT 64
#define C_IN  64
#define P_TOTAL 36864
#define N_PATCH 512
#define WSTR 72          // shorts per (r,c) cell in conv window LDS (144B, 16B-aligned)
#define GPLANE 1032      // shorts per k8-plane in wgen LDS (516 dwords = 4 mod 32 -> conflict-free)

typedef __bf16 bf16x8 __attribute__((ext_vector_type(8)));
typedef float  f32x4  __attribute__((ext_vector_type(4)));

__device__ __forceinline__ unsigned short f2bf(float f) {
  unsigned int u = __float_as_uint(f);
  u += 0x7fffu + ((u >> 16) & 1u);   // RTNE on bf16 boundary
  return (unsigned short)(u >> 16);
}

// ---------- prep 1: s2w -> bf16, rows permuted p(m) = co*576 + ci*9 + tap, m=(co,tap,ci) ----------
__global__ __launch_bounds__(256) void prep_s2w(
    const float* __restrict__ s2w, unsigned short* __restrict__ A0) {
  const int gid = blockIdx.x * 256 + threadIdx.x;   // 4608 blocks: 36864 rows x 8 float4
  const int m = gid >> 5;
  const int k4 = (gid & 31) * 4;
  const int co = m / 576;
  const int r = m - co * 576;
  const int tap = r >> 6;
  const int ci = r & 63;
  const int p = co * 576 + ci * 9 + tap;
  const float4 v = *(const float4*)(s2w + (size_t)p * 128 + k4);
  ushort4 o;
  o.x = f2bf(v.x); o.y = f2bf(v.y); o.z = f2bf(v.z); o.w = f2bf(v.w);
  *(ushort4*)(A0 + (size_t)m * 128 + k4) = o;
}

// ---------- prep 2: s -> sT bf16 [patch][k] ----------
__global__ __launch_bounds__(256) void prep_s(
    const float* __restrict__ s, unsigned short* __restrict__ sT) {
  const int bb = blockIdx.x;        // 2
  const int fg = threadIdx.x;       // 256
  unsigned short* dst = sT + ((size_t)bb * 256 + fg) * 128;
  for (int k = 0; k < 128; k += 2) {
    const float a = s[(size_t)(bb * 128 + k) * 256 + fg];
    const float b = s[(size_t)(bb * 128 + k + 1) * 256 + fg];
    const unsigned int u = (unsigned int)f2bf(a) | ((unsigned int)f2bf(b) << 16);
    *(unsigned int*)(dst + k) = u;
  }
}

// ---------- prep 3: x -> xT bf16 channel-last [b][h][w][ci] ----------
__global__ __launch_bounds__(256) void prep_x(
    const float* __restrict__ x, unsigned short* __restrict__ xT) {
  __shared__ unsigned short lds[256 * 68];   // stride 68 shorts: 2-way (free) banks both phases
  const int bb = blockIdx.x >> 8;
  const int row = blockIdx.x & 255;
  const int t = threadIdx.x;
  const float* src = x + ((size_t)bb * 64) * 65536 + row * 256 + t;
  #pragma unroll 8
  for (int ci = 0; ci < 64; ++ci)
    lds[t * 68 + ci] = f2bf(src[(size_t)ci * 65536]);
  __syncthreads();
  unsigned short* dst = xT + ((size_t)(bb * 65536 + row * 256 + t)) * 64;
  #pragma unroll
  for (int k8 = 0; k8 < 8; ++k8) {
    const uint2 u0 = *(const uint2*)&lds[t * 68 + k8 * 8];
    const uint2 u1 = *(const uint2*)&lds[t * 68 + k8 * 8 + 4];
    *(uint4*)(dst + k8 * 8) = make_uint4(u0.x, u0.y, u1.x, u1.y);
  }
}

// ---------- wgen: MFMA GEMM, 128x128 tile, K=128 single pass ----------
// LDS layout per operand: 16 planes (g = k>>3), plane = 128 rows x 8 shorts (+8 pad).
// a-frag/b-frag: lane reads 16B at [g=ks*4+quad][rowbase + (lane&15)] -> conflict-free.
__global__ __launch_bounds__(256) void wgen_kernel(
    const unsigned short* __restrict__ A0,   // bf16 [36864][128], pi-ordered
    const unsigned short* __restrict__ sT,   // bf16 [512][128]
    unsigned short* __restrict__ wout)       // bf16 frags [512][36864]
{
  __shared__ unsigned short As[16 * GPLANE];  // 33 KB
  __shared__ unsigned short Bs[16 * GPLANE];  // 33 KB
  const int tid = threadIdx.x;
  const int m0 = blockIdx.x * 128;   // 288
  const int n0 = blockIdx.y * 128;   // 4

  #pragma unroll
  for (int i = 0; i < 8; ++i) {      // 2048 16B-chunks per operand
    const int chunk = i * 256 + tid;
    const int row = chunk >> 4;
    const int g = chunk & 15;
    *(uint4*)&As[g * GPLANE + row * 8] = *(const uint4*)(A0 + ((size_t)(m0 + row)) * 128 + g * 8);
    *(uint4*)&Bs[g * GPLANE + row * 8] = *(const uint4*)(sT + ((size_t)(n0 + row)) * 128 + g * 8);
  }
  __syncthreads();

  const int wave = tid >> 6;
  const int lane = tid & 63;
  const int col = lane & 15;
  const int quad = lane >> 4;

  f32x4 acc[2][8] = {};              // [mti][nt]
  #pragma unroll
  for (int ks = 0; ks < 4; ++ks) {
    const int g = ks * 4 + quad;
    bf16x8 afr[2], bfr[8];
    #pragma unroll
    for (int mti = 0; mti < 2; ++mti)
      afr[mti] = *(const bf16x8*)&As[g * GPLANE + ((wave * 2 + mti) * 16 + col) * 8];
    #pragma unroll
    for (int nt = 0; nt < 8; ++nt)
      bfr[nt] = *(const bf16x8*)&Bs[g * GPLANE + (nt * 16 + col) * 8];
    #pragma unroll
    for (int mti = 0; mti < 2; ++mti)
      #pragma unroll
      for (int nt = 0; nt < 8; ++nt)
        acc[mti][nt] = __builtin_amdgcn_mfma_f32_16x16x32_bf16(afr[mti], bfr[nt], acc[mti][nt], 0, 0, 0);
  }

  // Epilogue: lane holds 4 consecutive m (= 4 consecutive ci at fixed co,tap) per acc tile.
  #pragma unroll
  for (int mti = 0; mti < 2; ++mti) {
    const int mbase = m0 + (wave * 2 + mti) * 16 + quad * 4;   // ci-4-aligned
    const int co = mbase / 576;
    const int rm = mbase - co * 576;
    const int tap = rm >> 6;
    const int ci = rm & 63;
    const size_t fragoff =
        ((size_t)((tap * 2 + (ci >> 5)) * 4 + (co >> 4)) * 64 + (co & 15) + 16 * ((ci >> 3) & 3)) * 8
        + (ci & 7);
    #pragma unroll
    for (int nt = 0; nt < 8; ++nt) {
      const int patch = n0 + nt * 16 + col;
      ushort4 o;
      o.x = f2bf(acc[mti][nt][0]); o.y = f2bf(acc[mti][nt][1]);
      o.z = f2bf(acc[mti][nt][2]); o.w = f2bf(acc[mti][nt][3]);
      *(ushort4*)(wout + (size_t)patch * P_TOTAL + fragoff) = o;
    }
  }
}

// ---------- conv: per-patch MFMA (round-2 verified core; staging from xT) ----------
__global__ __launch_bounds__(256) void conv_kernel(
    const unsigned short* __restrict__ xT,     // bf16 [2][256][256][64]
    const unsigned short* __restrict__ wfrag,  // bf16 frags [512][36864]
    float* __restrict__ out)                   // [2][64][256][256]
{
  __shared__ unsigned short win[324 * WSTR];   // 46656 B
  const int tid = threadIdx.x;
  const int patch = blockIdx.x;
  const int bb = patch >> 8;
  const int fg = patch & 255;
  const int f = fg >> 4, g = fg & 15;
  const int row0 = f * 16, col0 = g * 16;

  // Stage window: 324 cells x 64 ci, 16B chunks (8 per cell).
  for (int chunk = tid; chunk < 2592; chunk += 256) {
    const int cell = chunk >> 3;
    const int j = chunk & 7;
    const int r = cell / 18;
    const int c = cell - r * 18;
    int rr = row0 + r - 1; rr = rr < 0 ? -rr : (rr > 255 ? 510 - rr : rr);
    int cc = col0 + c - 1; cc = cc < 0 ? -cc : (cc > 255 ? 510 - cc : cc);
    *(uint4*)&win[cell * WSTR + j * 8] =
        *(const uint4*)(xT + ((size_t)((bb << 16) + (rr << 8) + cc)) * 64 + j * 8);
  }
  __syncthreads();

  const int wave = tid >> 6;
  const int lane = tid & 63;
  const int t = lane & 15;        // pixel column q
  const int quad = lane >> 4;

  f32x4 acc[4][4] = {};           // [mt=co/16][nt=p row]
  const bf16x8* wb = (const bf16x8*)(wfrag + (size_t)patch * P_TOTAL);

  for (int tap = 0; tap < 9; ++tap) {
    const int ti = tap / 3;
    const int tj = tap - ti * 3;
    bf16x8 afr[2][4];
    #pragma unroll
    for (int ks = 0; ks < 2; ++ks)
      #pragma unroll
      for (int mt = 0; mt < 4; ++mt)
        afr[ks][mt] = wb[((tap * 2 + ks) * 4 + mt) * 64 + lane];

    #pragma unroll
    for (int nt = 0; nt < 4; ++nt) {
      const int r = wave * 4 + nt + ti;
      const int c = t + tj;
      const int base = (r * 18 + c) * WSTR + quad * 8;
      #pragma unroll
      for (int ks = 0; ks < 2; ++ks) {
        const bf16x8 bfr = *(const bf16x8*)&win[base + ks * 32];
        #pragma unroll
        for (int mt = 0; mt < 4; ++mt)
          acc[mt][nt] = __builtin_amdgcn_mfma_f32_16x16x32_bf16(afr[ks][mt], bfr, acc[mt][nt], 0, 0, 0);
      }
    }
  }

  #pragma unroll
  for (int mt = 0; mt < 4; ++mt) {
    #pragma unroll
    for (int nt = 0; nt < 4; ++nt) {
      const int p = row0 + wave * 4 + nt;
      #pragma unroll
      for (int reg = 0; reg < 4; ++reg) {
        const int co = mt * 16 + quad * 4 + reg;
        out[(((size_t)bb * C_OUT + co) << 16) + ((size_t)p << 8) + col0 + t] = acc[mt][nt][reg];
      }
    }
  }
}

extern "C" void kernel_launch(void* const* d_in, const int* in_sizes, int n_in,
                              void* d_out, int out_size, void* d_ws, size_t ws_size,
                              hipStream_t stream) {
  const float* x   = (const float*)d_in[0];   // [2,64,256,256]
  const float* s   = (const float*)d_in[1];   // [2,128,16,16]
  const float* s2w = (const float*)d_in[2];   // [36864,128]
  float* out = (float*)d_out;

  char* ws = (char*)d_ws;
  unsigned short* wbuf = (unsigned short*)(ws);                 // 37,748,736 B
  unsigned short* A0   = (unsigned short*)(ws + 37748736);      //  9,437,184 B
  unsigned short* sT   = (unsigned short*)(ws + 47185920);      //    131,072 B
  unsigned short* xT   = (unsigned short*)(ws + 47316992);      // 16,777,216 B  (total 64.1 MB)

  prep_s2w<<<4608, 256, 0, stream>>>(s2w, A0);
  prep_s<<<2, 256, 0, stream>>>(s, sT);
  prep_x<<<512, 256, 0, stream>>>(x, xT);
  wgen_kernel<<<dim3(288, 4), 256, 0, stream>>>(A0, sT, wbuf);
  conv_kernel<<<N_PATCH, 256, 0, stream>>>(xT, wbuf, out);
}

// Round 4
// 139.669 us; speedup vs baseline: 2.6748x; 1.1182x over previous
//
#include <hip/hip_runtime.h>
#include <hip/hip_bf16.h>

// HyperPatchConv2d: B=2, CIN=COUT=64, H=W=256, FH=FW=16 (16x16 patches), SC=128, K=3, reflect pad.
// Pipeline (4 kernels):
//   prep_s: s fp32 [2][128][256] -> sT bf16 [512 patch][128 k]
//   prep_x: x fp32 [2][64][256][256] -> xT bf16 [2][256][256][64ci] (channel-last)
//   wgen:   MFMA GEMM with M-index == conv-fragment linear offset o:
//             o = fragidx*512 + lane*8 + j, fragidx=(tap*2+ks)*4+mt, lane=(co&15)+16*quad,
//             ci = ks*32+quad*8+j, co = mt*16+(lane&15), p(s2w row) = co*576+ci*9+tap.
//           A staged directly from fp32 s2w (permute+f2bf in staging). Epilogue transposes
//           the C-tile through LDS so each patch gets one contiguous 256B store (no write amp).
//   conv:   per-patch 9-tap MFMA GEMM (verified core), 8 waves x 2 rows.

#define C_OUT 64
#define C_IN  64
#define P_TOTAL 36864
#define N_PATCH 512
#define WSTR 72          // shorts per (r,c) cell in conv window LDS (144B)
#define GPLANE 1032      // shorts per k8-plane in wgen LDS (516 dwords = 4 mod 32)
#define CSTR 136         // shorts per patch-row in wgen epilogue LDS (272B, 16B-aligned)

typedef __bf16 bf16x8 __attribute__((ext_vector_type(8)));
typedef float  f32x4  __attribute__((ext_vector_type(4)));

__device__ __forceinline__ unsigned short f2bf(float f) {
  unsigned int u = __float_as_uint(f);
  u += 0x7fffu + ((u >> 16) & 1u);   // RTNE on bf16 boundary
  return (unsigned short)(u >> 16);
}

// ---------- prep 1: s -> sT bf16 [patch][k] ----------
__global__ __launch_bounds__(256) void prep_s(
    const float* __restrict__ s, unsigned short* __restrict__ sT) {
  const int bb = blockIdx.x;        // 2
  const int fg = threadIdx.x;       // 256
  unsigned short* dst = sT + ((size_t)bb * 256 + fg) * 128;
  for (int k = 0; k < 128; k += 2) {
    const float a = s[(size_t)(bb * 128 + k) * 256 + fg];
    const float b = s[(size_t)(bb * 128 + k + 1) * 256 + fg];
    const unsigned int u = (unsigned int)f2bf(a) | ((unsigned int)f2bf(b) << 16);
    *(unsigned int*)(dst + k) = u;
  }
}

// ---------- prep 2: x -> xT bf16 channel-last [b][h][w][ci] ----------
__global__ __launch_bounds__(256) void prep_x(
    const float* __restrict__ x, unsigned short* __restrict__ xT) {
  __shared__ unsigned short lds[256 * 68];
  const int bb = blockIdx.x >> 8;
  const int row = blockIdx.x & 255;
  const int t = threadIdx.x;
  const float* src = x + ((size_t)bb * 64) * 65536 + row * 256 + t;
  #pragma unroll 8
  for (int ci = 0; ci < 64; ++ci)
    lds[t * 68 + ci] = f2bf(src[(size_t)ci * 65536]);
  __syncthreads();
  unsigned short* dst = xT + ((size_t)(bb * 65536 + row * 256 + t)) * 64;
  #pragma unroll
  for (int k8 = 0; k8 < 8; ++k8) {
    const uint2 u0 = *(const uint2*)&lds[t * 68 + k8 * 8];
    const uint2 u1 = *(const uint2*)&lds[t * 68 + k8 * 8 + 4];
    *(uint4*)(dst + k8 * 8) = make_uint4(u0.x, u0.y, u1.x, u1.y);
  }
}

// ---------- wgen: MFMA GEMM, 128x128 tile, K=128, fused permute-in + transpose-out ----------
__global__ __launch_bounds__(256) void wgen_kernel(
    const float* __restrict__ s2w,          // fp32 [36864][128]
    const unsigned short* __restrict__ sT,  // bf16 [512][128]
    unsigned short* __restrict__ wout)      // bf16 frags [512][36864], offset o == m
{
  __shared__ unsigned short smem[2 * 16 * GPLANE];   // 66 KB; reused as Ct in epilogue
  unsigned short* As = smem;
  unsigned short* Bs = smem + 16 * GPLANE;
  const int tid = threadIdx.x;
  const int m0 = blockIdx.x * 128;   // 288 blocks in m
  const int n0 = blockIdx.y * 128;   // 4 blocks in patch

  // Per-block frag decode (m-range 128 stays inside one fragidx group of 512)
  const int fragidx = m0 >> 9;
  const int tap = fragidx >> 3;
  const int ksH = (fragidx >> 2) & 1;
  const int mtH = fragidx & 3;

  // A staging: read s2w row p(m) fp32 (32B per 16B bf16 chunk), coalesced; f2bf -> plane LDS
  #pragma unroll
  for (int i = 0; i < 8; ++i) {
    const int chunk = i * 256 + tid;        // 2048 chunks: 128 rows x 16 planes
    const int row = chunk >> 4;
    const int g = chunk & 15;
    const int m = m0 + row;
    const int j = m & 7;
    const int lane6 = (m >> 3) & 63;
    const int co = mtH * 16 + (lane6 & 15);
    const int ci = ksH * 32 + (lane6 >> 4) * 8 + j;
    const int p = co * 576 + ci * 9 + tap;
    const float* src = s2w + (size_t)p * 128 + g * 8;
    const float4 v0 = *(const float4*)src;
    const float4 v1 = *(const float4*)(src + 4);
    uint4 o;
    o.x = (unsigned int)f2bf(v0.x) | ((unsigned int)f2bf(v0.y) << 16);
    o.y = (unsigned int)f2bf(v0.z) | ((unsigned int)f2bf(v0.w) << 16);
    o.z = (unsigned int)f2bf(v1.x) | ((unsigned int)f2bf(v1.y) << 16);
    o.w = (unsigned int)f2bf(v1.z) | ((unsigned int)f2bf(v1.w) << 16);
    *(uint4*)&As[g * GPLANE + row * 8] = o;
  }
  // B staging: bf16 sT, 16B chunks
  #pragma unroll
  for (int i = 0; i < 8; ++i) {
    const int chunk = i * 256 + tid;
    const int row = chunk >> 4;
    const int g = chunk & 15;
    *(uint4*)&Bs[g * GPLANE + row * 8] = *(const uint4*)(sT + ((size_t)(n0 + row)) * 128 + g * 8);
  }
  __syncthreads();

  const int wave = tid >> 6;
  const int lane = tid & 63;
  const int col = lane & 15;
  const int quad = lane >> 4;

  f32x4 acc[2][8] = {};              // [mti][nt]
  #pragma unroll
  for (int ks = 0; ks < 4; ++ks) {
    const int g = ks * 4 + quad;
    bf16x8 afr[2], bfr[8];
    #pragma unroll
    for (int mti = 0; mti < 2; ++mti)
      afr[mti] = *(const bf16x8*)&As[g * GPLANE + ((wave * 2 + mti) * 16 + col) * 8];
    #pragma unroll
    for (int nt = 0; nt < 8; ++nt)
      bfr[nt] = *(const bf16x8*)&Bs[g * GPLANE + (nt * 16 + col) * 8];
    #pragma unroll
    for (int mti = 0; mti < 2; ++mti)
      #pragma unroll
      for (int nt = 0; nt < 8; ++nt)
        acc[mti][nt] = __builtin_amdgcn_mfma_f32_16x16x32_bf16(afr[mti], bfr[nt], acc[mti][nt], 0, 0, 0);
  }

  // Epilogue: transpose C (128m x 128patch) through LDS -> contiguous 256B store per patch.
  __syncthreads();                   // all frag reads done; reuse smem
  unsigned short* Ct = smem;         // [128 patch][CSTR], 34.8 KB
  #pragma unroll
  for (int mti = 0; mti < 2; ++mti) {
    const int mloc = (wave * 2 + mti) * 16 + quad * 4;
    #pragma unroll
    for (int nt = 0; nt < 8; ++nt) {
      const int pl = nt * 16 + col;
      ushort4 o;
      o.x = f2bf(acc[mti][nt][0]); o.y = f2bf(acc[mti][nt][1]);
      o.z = f2bf(acc[mti][nt][2]); o.w = f2bf(acc[mti][nt][3]);
      *(ushort4*)&Ct[pl * CSTR + mloc] = o;
    }
  }
  __syncthreads();
  #pragma unroll
  for (int i = 0; i < 8; ++i) {
    const int chunk = i * 256 + tid;        // 2048: 128 patches x 16 chunks of 16B
    const int pl = chunk >> 4;
    const int ii = chunk & 15;
    const uint4 v = *(const uint4*)&Ct[pl * CSTR + ii * 8];
    *(uint4*)(wout + (size_t)(n0 + pl) * P_TOTAL + m0 + ii * 8) = v;
  }
}

// ---------- conv: per-patch MFMA (verified core), 8 waves x 2 rows ----------
__global__ __launch_bounds__(512) void conv_kernel(
    const unsigned short* __restrict__ xT,     // bf16 [2][256][256][64]
    const unsigned short* __restrict__ wfrag,  // bf16 frags [512][36864]
    float* __restrict__ out)                   // [2][64][256][256]
{
  __shared__ unsigned short win[324 * WSTR];   // 46656 B
  const int tid = threadIdx.x;
  const int patch = blockIdx.x;
  const int bb = patch >> 8;
  const int fg = patch & 255;
  const int f = fg >> 4, g = fg & 15;
  const int row0 = f * 16, col0 = g * 16;

  for (int chunk = tid; chunk < 2592; chunk += 512) {
    const int cell = chunk >> 3;
    const int j = chunk & 7;
    const int r = cell / 18;
    const int c = cell - r * 18;
    int rr = row0 + r - 1; rr = rr < 0 ? -rr : (rr > 255 ? 510 - rr : rr);
    int cc = col0 + c - 1; cc = cc < 0 ? -cc : (cc > 255 ? 510 - cc : cc);
    *(uint4*)&win[cell * WSTR + j * 8] =
        *(const uint4*)(xT + ((size_t)((bb << 16) + (rr << 8) + cc)) * 64 + j * 8);
  }
  __syncthreads();

  const int wave = tid >> 6;      // 0..7, rows wave*2..wave*2+1
  const int lane = tid & 63;
  const int t = lane & 15;
  const int quad = lane >> 4;

  f32x4 acc[4][2] = {};           // [mt][nt]
  const bf16x8* wb = (const bf16x8*)(wfrag + (size_t)patch * P_TOTAL);

  for (int tap = 0; tap < 9; ++tap) {
    const int ti = tap / 3;
    const int tj = tap - ti * 3;
    bf16x8 afr[2][4];
    #pragma unroll
    for (int ks = 0; ks < 2; ++ks)
      #pragma unroll
      for (int mt = 0; mt < 4; ++mt)
        afr[ks][mt] = wb[((tap * 2 + ks) * 4 + mt) * 64 + lane];

    #pragma unroll
    for (int nt = 0; nt < 2; ++nt) {
      const int r = wave * 2 + nt + ti;
      const int c = t + tj;
      const int base = (r * 18 + c) * WSTR + quad * 8;
      #pragma unroll
      for (int ks = 0; ks < 2; ++ks) {
        const bf16x8 bfr = *(const bf16x8*)&win[base + ks * 32];
        #pragma unroll
        for (int mt = 0; mt < 4; ++mt)
          acc[mt][nt] = __builtin_amdgcn_mfma_f32_16x16x32_bf16(afr[ks][mt], bfr, acc[mt][nt], 0, 0, 0);
      }
    }
  }

  #pragma unroll
  for (int mt = 0; mt < 4; ++mt) {
    #pragma unroll
    for (int nt = 0; nt < 2; ++nt) {
      const int p = row0 + wave * 2 + nt;
      #pragma unroll
      for (int reg = 0; reg < 4; ++reg) {
        const int co = mt * 16 + quad * 4 + reg;
        out[(((size_t)bb * C_OUT + co) << 16) + ((size_t)p << 8) + col0 + t] = acc[mt][nt][reg];
      }
    }
  }
}

extern "C" void kernel_launch(void* const* d_in, const int* in_sizes, int n_in,
                              void* d_out, int out_size, void* d_ws, size_t ws_size,
                              hipStream_t stream) {
  const float* x   = (const float*)d_in[0];   // [2,64,256,256]
  const float* s   = (const float*)d_in[1];   // [2,128,16,16]
  const float* s2w = (const float*)d_in[2];   // [36864,128]
  float* out = (float*)d_out;

  char* ws = (char*)d_ws;
  unsigned short* wbuf = (unsigned short*)(ws);              // 37,748,736 B
  unsigned short* sT   = (unsigned short*)(ws + 37748736);   //    131,072 B
  unsigned short* xT   = (unsigned short*)(ws + 37879808);   // 16,777,216 B (total 54.7 MB)

  prep_s<<<2, 256, 0, stream>>>(s, sT);
  prep_x<<<512, 256, 0, stream>>>(x, xT);
  wgen_kernel<<<dim3(288, 4), 256, 0, stream>>>(s2w, sT, wbuf);
  conv_kernel<<<N_PATCH, 512, 0, stream>>>(xT, wbuf, out);
}